// Round 1
// baseline (45.674 us; speedup 1.0000x reference)
//
#include <hip/hip_runtime.h>
#include <math.h>

#define BS    64
#define NPTS  10000
#define D     128
#define MM    16
#define SG    1000
#define SPLIT 10
#define PER   (SG / SPLIT)   // 100 indices per split-block, exact

__device__ __forceinline__ float gelu_f(float x) {
    // JAX default: approximate (tanh) GELU
    float x3 = x * x * x;
    return 0.5f * x * (1.0f + tanhf(0.7978845608028654f * (x + 0.044715f * x3)));
}

// Sum of v across 128 threads, broadcast to all. red is a 128-float LDS buffer.
__device__ __forceinline__ float block_sum128(float v, float* red, int d) {
    __syncthreads();            // protect any prior use of red
    red[d] = v;
    __syncthreads();
    #pragma unroll
    for (int s = 64; s > 0; s >>= 1) {
        if (d < s) red[d] += red[d + s];
        __syncthreads();
    }
    return red[0];
}

__global__ __launch_bounds__(128) void pool_kernel(
    const float* __restrict__ node_emb, const int* __restrict__ sg_idx,
    float* __restrict__ ws_sum, float* __restrict__ ws_max)
{
    const int b  = blockIdx.x / SPLIT;
    const int sp = blockIdx.x % SPLIT;
    const int t  = threadIdx.x;
    const int g  = t >> 5;   // row group 0..3
    const int c  = t & 31;   // channel quad 0..31 (covers 4 floats)

    const float* __restrict__ base = node_emb + (size_t)b * NPTS * D;
    const int*   __restrict__ ib   = sg_idx + b * SG + sp * PER;

    float4 s = make_float4(0.f, 0.f, 0.f, 0.f);
    float4 m = make_float4(-INFINITY, -INFINITY, -INFINITY, -INFINITY);

    #pragma unroll 5
    for (int j = 0; j < PER / 4; ++j) {      // 25 iterations, 4 rows each
        int id = ib[j * 4 + g];
        float4 v = *(const float4*)(base + (size_t)id * D + c * 4);
        // node_emb[:,0] is treated as the zero vector (depot sentinel)
        float msk = (id != 0) ? 1.f : 0.f;
        v.x *= msk; v.y *= msk; v.z *= msk; v.w *= msk;
        s.x += v.x; s.y += v.y; s.z += v.z; s.w += v.w;
        m.x = fmaxf(m.x, v.x); m.y = fmaxf(m.y, v.y);
        m.z = fmaxf(m.z, v.z); m.w = fmaxf(m.w, v.w);
    }

    __shared__ float ssum[4][D];
    __shared__ float smax[4][D];
    ssum[g][c * 4 + 0] = s.x; ssum[g][c * 4 + 1] = s.y;
    ssum[g][c * 4 + 2] = s.z; ssum[g][c * 4 + 3] = s.w;
    smax[g][c * 4 + 0] = m.x; smax[g][c * 4 + 1] = m.y;
    smax[g][c * 4 + 2] = m.z; smax[g][c * 4 + 3] = m.w;
    __syncthreads();

    const int d = t;  // 128 threads == D channels
    float fs = ssum[0][d] + ssum[1][d] + ssum[2][d] + ssum[3][d];
    float fm = fmaxf(fmaxf(smax[0][d], smax[1][d]), fmaxf(smax[2][d], smax[3][d]));
    ws_sum[(b * SPLIT + sp) * D + d] = fs;
    ws_max[(b * SPLIT + sp) * D + d] = fm;
}

__global__ __launch_bounds__(128) void mlp_kernel(
    const float* __restrict__ ws_sum, const float* __restrict__ ws_max,
    const float* __restrict__ graph_emb, const float* __restrict__ meta,
    const float* __restrict__ sg_w1, const float* __restrict__ sg_b1,
    const float* __restrict__ sg_g,  const float* __restrict__ sg_bt,
    const float* __restrict__ sg_w2, const float* __restrict__ sg_b2,
    const float* __restrict__ mf_w1, const float* __restrict__ mf_b1,
    const float* __restrict__ mf_g,  const float* __restrict__ mf_bt,
    const float* __restrict__ mf_w2, const float* __restrict__ mf_b2,
    const float* __restrict__ cx_w1, const float* __restrict__ cx_b1,
    const float* __restrict__ cx_w2, const float* __restrict__ cx_b2,
    float* __restrict__ out)
{
    const int b = blockIdx.x;
    const int d = threadIdx.x;

    __shared__ float xbuf[2 * D];
    __shared__ float hbuf[D];
    __shared__ float red[D];

    // finish the pooling reduction
    float psum = 0.f, pmax = -INFINITY;
    #pragma unroll
    for (int sp = 0; sp < SPLIT; ++sp) {
        psum += ws_sum[(b * SPLIT + sp) * D + d];
        pmax = fmaxf(pmax, ws_max[(b * SPLIT + sp) * D + d]);
    }
    xbuf[d] = psum;       // pooled[0:128]  = sum
    xbuf[D + d] = pmax;   // pooled[128:256] = max
    __syncthreads();

    // ---- sg branch: Linear(256->128) -> LN -> GELU -> Linear(128->128)
    float h = sg_b1[d];
    #pragma unroll 8
    for (int k = 0; k < 2 * D; ++k) h = fmaf(xbuf[k], sg_w1[k * D + d], h);
    float mu  = block_sum128(h, red, d) * (1.f / D);
    float cd  = h - mu;
    float var = block_sum128(cd * cd, red, d) * (1.f / D);
    float hg  = gelu_f(cd * rsqrtf(var + 1e-5f) * sg_g[d] + sg_bt[d]);
    __syncthreads();
    hbuf[d] = hg;
    __syncthreads();
    float o_sg = sg_b2[d];
    #pragma unroll 8
    for (int k = 0; k < D; ++k) o_sg = fmaf(hbuf[k], sg_w2[k * D + d], o_sg);

    // ---- mf branch: Linear(16->128) -> LN -> GELU -> Linear(128->128)
    float h2 = mf_b1[d];
    #pragma unroll
    for (int k = 0; k < MM; ++k) h2 = fmaf(meta[b * MM + k], mf_w1[k * D + d], h2);
    float mu2  = block_sum128(h2, red, d) * (1.f / D);
    float cd2  = h2 - mu2;
    float var2 = block_sum128(cd2 * cd2, red, d) * (1.f / D);
    float hg2  = gelu_f(cd2 * rsqrtf(var2 + 1e-5f) * mf_g[d] + mf_bt[d]);
    __syncthreads();            // all prior reads of hbuf are done (block_sum synced)
    hbuf[d] = hg2;
    __syncthreads();
    float o_mf = mf_b2[d];
    #pragma unroll 8
    for (int k = 0; k < D; ++k) o_mf = fmaf(hbuf[k], mf_w2[k * D + d], o_mf);

    float sg_emb = o_sg + o_mf;
    out[b * D + d] = sg_emb;

    // ---- ctxt branch: Linear(256->128) -> GELU -> Linear(128->128)
    __syncthreads();
    xbuf[d] = sg_emb;
    xbuf[D + d] = graph_emb[b * D + d];
    __syncthreads();
    float ch = cx_b1[d];
    #pragma unroll 8
    for (int k = 0; k < 2 * D; ++k) ch = fmaf(xbuf[k], cx_w1[k * D + d], ch);
    float cg = gelu_f(ch);
    __syncthreads();
    hbuf[d] = cg;
    __syncthreads();
    float o_cx = cx_b2[d];
    #pragma unroll 8
    for (int k = 0; k < D; ++k) o_cx = fmaf(hbuf[k], cx_w2[k * D + d], o_cx);
    out[BS * D + b * D + d] = o_cx;
}

extern "C" void kernel_launch(void* const* d_in, const int* in_sizes, int n_in,
                              void* d_out, int out_size, void* d_ws, size_t ws_size,
                              hipStream_t stream) {
    const float* node_emb  = (const float*)d_in[0];
    const float* graph_emb = (const float*)d_in[1];
    const int*   sg_idx    = (const int*)d_in[2];
    const float* meta      = (const float*)d_in[3];
    const float* sg_w1 = (const float*)d_in[4];
    const float* sg_b1 = (const float*)d_in[5];
    const float* sg_g  = (const float*)d_in[6];
    const float* sg_bt = (const float*)d_in[7];
    const float* sg_w2 = (const float*)d_in[8];
    const float* sg_b2 = (const float*)d_in[9];
    const float* mf_w1 = (const float*)d_in[10];
    const float* mf_b1 = (const float*)d_in[11];
    const float* mf_g  = (const float*)d_in[12];
    const float* mf_bt = (const float*)d_in[13];
    const float* mf_w2 = (const float*)d_in[14];
    const float* mf_b2 = (const float*)d_in[15];
    const float* cx_w1 = (const float*)d_in[16];
    const float* cx_b1 = (const float*)d_in[17];
    const float* cx_w2 = (const float*)d_in[18];
    const float* cx_b2 = (const float*)d_in[19];

    float* out    = (float*)d_out;
    float* ws     = (float*)d_ws;
    float* ws_sum = ws;                       // BS*SPLIT*D floats
    float* ws_max = ws + BS * SPLIT * D;      // BS*SPLIT*D floats (total 640 KB)

    pool_kernel<<<BS * SPLIT, 128, 0, stream>>>(node_emb, sg_idx, ws_sum, ws_max);
    mlp_kernel<<<BS, 128, 0, stream>>>(ws_sum, ws_max, graph_emb, meta,
        sg_w1, sg_b1, sg_g, sg_bt, sg_w2, sg_b2,
        mf_w1, mf_b1, mf_g, mf_bt, mf_w2, mf_b2,
        cx_w1, cx_b1, cx_w2, cx_b2, out);
}

// Round 2
// 45.390 us; speedup vs baseline: 1.0063x; 1.0063x over previous
//
#include <hip/hip_runtime.h>
#include <math.h>

#define BS    64
#define NPTS  10000
#define D     128
#define MM    16
#define SG    1000
#define SPLIT 25
#define PER   (SG / SPLIT)   // 40 rows per block
#define RITER (PER / 8)      // 5 iterations of 8 rows (256 threads = 8 row-groups x 32 lanes)

__device__ __forceinline__ float gelu_f(float x) {
    // JAX default: approximate (tanh) GELU
    float x3 = x * x * x;
    return 0.5f * x * (1.0f + tanhf(0.7978845608028654f * (x + 0.044715f * x3)));
}

// Sum of v across 128 threads, broadcast to all. red is a 128-float LDS buffer.
__device__ __forceinline__ float block_sum128(float v, float* red, int d) {
    __syncthreads();            // protect any prior use of red
    red[d] = v;
    __syncthreads();
    #pragma unroll
    for (int s = 64; s > 0; s >>= 1) {
        if (d < s) red[d] += red[d + s];
        __syncthreads();
    }
    return red[0];
}

__global__ __launch_bounds__(256) void pool_kernel(
    const float* __restrict__ node_emb, const int* __restrict__ sg_idx,
    float* __restrict__ ws_sum, float* __restrict__ ws_max)
{
    const int b  = blockIdx.x / SPLIT;
    const int sp = blockIdx.x % SPLIT;
    const int t  = threadIdx.x;
    const int g  = t >> 5;   // row group 0..7
    const int c  = t & 31;   // channel quad 0..31 (covers 4 floats)

    const float* __restrict__ base = node_emb + (size_t)b * NPTS * D;
    const int*   __restrict__ ib   = sg_idx + b * SG + sp * PER;

    // Preload all indices -> registers so the 5 gathers are independent
    int ids[RITER];
    #pragma unroll
    for (int j = 0; j < RITER; ++j) ids[j] = ib[j * 8 + g];

    float4 s = make_float4(0.f, 0.f, 0.f, 0.f);
    float4 m = make_float4(-INFINITY, -INFINITY, -INFINITY, -INFINITY);

    #pragma unroll
    for (int j = 0; j < RITER; ++j) {
        float4 v = *(const float4*)(base + (size_t)ids[j] * D + (c << 2));
        // node_emb[:,0] is treated as the zero vector (depot sentinel)
        float msk = (ids[j] != 0) ? 1.f : 0.f;
        v.x *= msk; v.y *= msk; v.z *= msk; v.w *= msk;
        s.x += v.x; s.y += v.y; s.z += v.z; s.w += v.w;
        m.x = fmaxf(m.x, v.x); m.y = fmaxf(m.y, v.y);
        m.z = fmaxf(m.z, v.z); m.w = fmaxf(m.w, v.w);
    }

    __shared__ float ssum[8][D];
    __shared__ float smax[8][D];
    ssum[g][c * 4 + 0] = s.x; ssum[g][c * 4 + 1] = s.y;
    ssum[g][c * 4 + 2] = s.z; ssum[g][c * 4 + 3] = s.w;
    smax[g][c * 4 + 0] = m.x; smax[g][c * 4 + 1] = m.y;
    smax[g][c * 4 + 2] = m.z; smax[g][c * 4 + 3] = m.w;
    __syncthreads();

    // 256 threads: first 128 reduce the sums, last 128 reduce the maxes
    if (t < D) {
        float fs = 0.f;
        #pragma unroll
        for (int r = 0; r < 8; ++r) fs += ssum[r][t];
        ws_sum[(b * SPLIT + sp) * D + t] = fs;
    } else {
        const int d = t - D;
        float fm = -INFINITY;
        #pragma unroll
        for (int r = 0; r < 8; ++r) fm = fmaxf(fm, smax[r][d]);
        ws_max[(b * SPLIT + sp) * D + d] = fm;
    }
}

__global__ __launch_bounds__(128) void mlp_kernel(
    const float* __restrict__ ws_sum, const float* __restrict__ ws_max,
    const float* __restrict__ graph_emb, const float* __restrict__ meta,
    const float* __restrict__ sg_w1, const float* __restrict__ sg_b1,
    const float* __restrict__ sg_g,  const float* __restrict__ sg_bt,
    const float* __restrict__ sg_w2, const float* __restrict__ sg_b2,
    const float* __restrict__ mf_w1, const float* __restrict__ mf_b1,
    const float* __restrict__ mf_g,  const float* __restrict__ mf_bt,
    const float* __restrict__ mf_w2, const float* __restrict__ mf_b2,
    const float* __restrict__ cx_w1, const float* __restrict__ cx_b1,
    const float* __restrict__ cx_w2, const float* __restrict__ cx_b2,
    float* __restrict__ out)
{
    const int b = blockIdx.x;
    const int d = threadIdx.x;

    __shared__ float xbuf[2 * D];
    __shared__ float hbuf[D];
    __shared__ float red[D];

    // finish the pooling reduction
    float psum = 0.f, pmax = -INFINITY;
    #pragma unroll
    for (int sp = 0; sp < SPLIT; ++sp) {
        psum += ws_sum[(b * SPLIT + sp) * D + d];
        pmax = fmaxf(pmax, ws_max[(b * SPLIT + sp) * D + d]);
    }
    xbuf[d] = psum;       // pooled[0:128]  = sum
    xbuf[D + d] = pmax;   // pooled[128:256] = max
    __syncthreads();

    // ---- sg branch: Linear(256->128) -> LN -> GELU -> Linear(128->128)
    float h = sg_b1[d];
    #pragma unroll 8
    for (int k = 0; k < 2 * D; ++k) h = fmaf(xbuf[k], sg_w1[k * D + d], h);
    float mu  = block_sum128(h, red, d) * (1.f / D);
    float cd  = h - mu;
    float var = block_sum128(cd * cd, red, d) * (1.f / D);
    float hg  = gelu_f(cd * rsqrtf(var + 1e-5f) * sg_g[d] + sg_bt[d]);
    __syncthreads();
    hbuf[d] = hg;
    __syncthreads();
    float o_sg = sg_b2[d];
    #pragma unroll 8
    for (int k = 0; k < D; ++k) o_sg = fmaf(hbuf[k], sg_w2[k * D + d], o_sg);

    // ---- mf branch: Linear(16->128) -> LN -> GELU -> Linear(128->128)
    float h2 = mf_b1[d];
    #pragma unroll
    for (int k = 0; k < MM; ++k) h2 = fmaf(meta[b * MM + k], mf_w1[k * D + d], h2);
    float mu2  = block_sum128(h2, red, d) * (1.f / D);
    float cd2  = h2 - mu2;
    float var2 = block_sum128(cd2 * cd2, red, d) * (1.f / D);
    float hg2  = gelu_f(cd2 * rsqrtf(var2 + 1e-5f) * mf_g[d] + mf_bt[d]);
    __syncthreads();            // all prior reads of hbuf are done (block_sum synced)
    hbuf[d] = hg2;
    __syncthreads();
    float o_mf = mf_b2[d];
    #pragma unroll 8
    for (int k = 0; k < D; ++k) o_mf = fmaf(hbuf[k], mf_w2[k * D + d], o_mf);

    float sg_emb = o_sg + o_mf;
    out[b * D + d] = sg_emb;

    // ---- ctxt branch: Linear(256->128) -> GELU -> Linear(128->128)
    __syncthreads();
    xbuf[d] = sg_emb;
    xbuf[D + d] = graph_emb[b * D + d];
    __syncthreads();
    float ch = cx_b1[d];
    #pragma unroll 8
    for (int k = 0; k < 2 * D; ++k) ch = fmaf(xbuf[k], cx_w1[k * D + d], ch);
    float cg = gelu_f(ch);
    __syncthreads();
    hbuf[d] = cg;
    __syncthreads();
    float o_cx = cx_b2[d];
    #pragma unroll 8
    for (int k = 0; k < D; ++k) o_cx = fmaf(hbuf[k], cx_w2[k * D + d], o_cx);
    out[BS * D + b * D + d] = o_cx;
}

extern "C" void kernel_launch(void* const* d_in, const int* in_sizes, int n_in,
                              void* d_out, int out_size, void* d_ws, size_t ws_size,
                              hipStream_t stream) {
    const float* node_emb  = (const float*)d_in[0];
    const float* graph_emb = (const float*)d_in[1];
    const int*   sg_idx    = (const int*)d_in[2];
    const float* meta      = (const float*)d_in[3];
    const float* sg_w1 = (const float*)d_in[4];
    const float* sg_b1 = (const float*)d_in[5];
    const float* sg_g  = (const float*)d_in[6];
    const float* sg_bt = (const float*)d_in[7];
    const float* sg_w2 = (const float*)d_in[8];
    const float* sg_b2 = (const float*)d_in[9];
    const float* mf_w1 = (const float*)d_in[10];
    const float* mf_b1 = (const float*)d_in[11];
    const float* mf_g  = (const float*)d_in[12];
    const float* mf_bt = (const float*)d_in[13];
    const float* mf_w2 = (const float*)d_in[14];
    const float* mf_b2 = (const float*)d_in[15];
    const float* cx_w1 = (const float*)d_in[16];
    const float* cx_b1 = (const float*)d_in[17];
    const float* cx_w2 = (const float*)d_in[18];
    const float* cx_b2 = (const float*)d_in[19];

    float* out    = (float*)d_out;
    float* ws     = (float*)d_ws;
    float* ws_sum = ws;                       // BS*SPLIT*D floats
    float* ws_max = ws + BS * SPLIT * D;      // BS*SPLIT*D floats (total 1.6 MB)

    pool_kernel<<<BS * SPLIT, 256, 0, stream>>>(node_emb, sg_idx, ws_sum, ws_max);
    mlp_kernel<<<BS, 128, 0, stream>>>(ws_sum, ws_max, graph_emb, meta,
        sg_w1, sg_b1, sg_g, sg_bt, sg_w2, sg_b2,
        mf_w1, mf_b1, mf_g, mf_bt, mf_w2, mf_b2,
        cx_w1, cx_b1, cx_w2, cx_b2, out);
}

// Round 3
// 28.672 us; speedup vs baseline: 1.5930x; 1.5830x over previous
//
#include <hip/hip_runtime.h>
#include <math.h>

#define BS    64
#define NPTS  10000
#define D     128
#define MM    16
#define SG    1000
#define SPLIT 25
#define PER   (SG / SPLIT)   // 40 rows per block
#define RITER (PER / 8)      // 5 iterations of 8 rows (256 threads = 8 row-groups x 32 lanes)

__device__ __forceinline__ float gelu_f(float x) {
    // JAX default: approximate (tanh) GELU
    float x3 = x * x * x;
    return 0.5f * x * (1.0f + tanhf(0.7978845608028654f * (x + 0.044715f * x3)));
}

__global__ __launch_bounds__(256) void pool_kernel(
    const float* __restrict__ node_emb, const int* __restrict__ sg_idx,
    float* __restrict__ ws_sum, float* __restrict__ ws_max)
{
    const int b  = blockIdx.x / SPLIT;
    const int sp = blockIdx.x % SPLIT;
    const int t  = threadIdx.x;
    const int g  = t >> 5;   // row group 0..7
    const int c  = t & 31;   // channel quad 0..31 (covers 4 floats)

    const float* __restrict__ base = node_emb + (size_t)b * NPTS * D;
    const int*   __restrict__ ib   = sg_idx + b * SG + sp * PER;

    // Preload all indices -> registers so the 5 gathers are independent
    int ids[RITER];
    #pragma unroll
    for (int j = 0; j < RITER; ++j) ids[j] = ib[j * 8 + g];

    float4 s = make_float4(0.f, 0.f, 0.f, 0.f);
    float4 m = make_float4(-INFINITY, -INFINITY, -INFINITY, -INFINITY);

    #pragma unroll
    for (int j = 0; j < RITER; ++j) {
        float4 v = *(const float4*)(base + (size_t)ids[j] * D + (c << 2));
        // node_emb[:,0] is treated as the zero vector (depot sentinel)
        float msk = (ids[j] != 0) ? 1.f : 0.f;
        v.x *= msk; v.y *= msk; v.z *= msk; v.w *= msk;
        s.x += v.x; s.y += v.y; s.z += v.z; s.w += v.w;
        m.x = fmaxf(m.x, v.x); m.y = fmaxf(m.y, v.y);
        m.z = fmaxf(m.z, v.z); m.w = fmaxf(m.w, v.w);
    }

    __shared__ float ssum[8][D];
    __shared__ float smax[8][D];
    ssum[g][c * 4 + 0] = s.x; ssum[g][c * 4 + 1] = s.y;
    ssum[g][c * 4 + 2] = s.z; ssum[g][c * 4 + 3] = s.w;
    smax[g][c * 4 + 0] = m.x; smax[g][c * 4 + 1] = m.y;
    smax[g][c * 4 + 2] = m.z; smax[g][c * 4 + 3] = m.w;
    __syncthreads();

    // 256 threads: first 128 reduce the sums, last 128 reduce the maxes
    if (t < D) {
        float fs = 0.f;
        #pragma unroll
        for (int r = 0; r < 8; ++r) fs += ssum[r][t];
        ws_sum[(b * SPLIT + sp) * D + t] = fs;
    } else {
        const int d = t - D;
        float fm = -INFINITY;
        #pragma unroll
        for (int r = 0; r < 8; ++r) fm = fmaxf(fm, smax[r][d]);
        ws_max[(b * SPLIT + sp) * D + d] = fm;
    }
}

// Sum over the 128 h-values held by the q==0 threads (d = 0..127).
// ALL 512 threads must call (contains __syncthreads). Returns the total.
__device__ __forceinline__ float block_sum_q0(float h, int t, int q, int d, float* red) {
    __syncthreads();
    if (q == 0) red[d] = h;
    __syncthreads();
    if (t < 64) {
        float v = red[t] + red[t + 64];
        #pragma unroll
        for (int off = 32; off; off >>= 1) v += __shfl_xor(v, off, 64);
        if (t == 0) red[0] = v;
    }
    __syncthreads();
    return red[0];
}

__global__ __launch_bounds__(512) void mlp_kernel(
    const float* __restrict__ ws_sum, const float* __restrict__ ws_max,
    const float* __restrict__ graph_emb, const float* __restrict__ meta,
    const float* __restrict__ sg_w1, const float* __restrict__ sg_b1,
    const float* __restrict__ sg_g,  const float* __restrict__ sg_bt,
    const float* __restrict__ sg_w2, const float* __restrict__ sg_b2,
    const float* __restrict__ mf_w1, const float* __restrict__ mf_b1,
    const float* __restrict__ mf_g,  const float* __restrict__ mf_bt,
    const float* __restrict__ mf_w2, const float* __restrict__ mf_b2,
    const float* __restrict__ cx_w1, const float* __restrict__ cx_b1,
    const float* __restrict__ cx_w2, const float* __restrict__ cx_b2,
    float* __restrict__ out)
{
    const int b = blockIdx.x;
    const int t = threadIdx.x;
    const int q = t >> 7;    // k-partial group 0..3
    const int d = t & 127;   // output channel

    __shared__ float xbuf[2 * D];
    __shared__ float part[4][D];
    __shared__ float hbuf[D];
    __shared__ float osum[D];
    __shared__ float red[D];

    // ---- phase 0: finish pooling reduction (q0/q1: sum halves, q2/q3: max halves)
    {
        float acc;
        if (q < 2) {
            acc = 0.f;
            const int s0 = q * 13, s1 = (q == 0) ? 13 : SPLIT;
            for (int sp = s0; sp < s1; ++sp) acc += ws_sum[(b * SPLIT + sp) * D + d];
        } else {
            acc = -INFINITY;
            const int s0 = (q - 2) * 13, s1 = (q == 2) ? 13 : SPLIT;
            for (int sp = s0; sp < s1; ++sp) acc = fmaxf(acc, ws_max[(b * SPLIT + sp) * D + d]);
        }
        part[q][d] = acc;
        __syncthreads();
        if (q == 0)      xbuf[d]     = part[0][d] + part[1][d];
        else if (q == 1) xbuf[D + d] = fmaxf(part[2][d], part[3][d]);
        __syncthreads();
    }

    // ---- sg GEMV1: pooled(256) @ sg_w1 -> h
    {
        float acc = 0.f;
        const int k0 = q * 64;
        #pragma unroll 8
        for (int kk = 0; kk < 64; ++kk)
            acc = fmaf(xbuf[k0 + kk], sg_w1[(k0 + kk) * D + d], acc);
        part[q][d] = acc;
        __syncthreads();
    }
    {
        float h = 0.f;
        if (q == 0) h = part[0][d] + part[1][d] + part[2][d] + part[3][d] + sg_b1[d];
        float mu  = block_sum_q0(h, t, q, d, red) * (1.f / D);
        float cd  = (q == 0) ? (h - mu) : 0.f;
        float var = block_sum_q0(cd * cd, t, q, d, red) * (1.f / D);
        if (q == 0) hbuf[d] = gelu_f(cd * rsqrtf(var + 1e-5f) * sg_g[d] + sg_bt[d]);
        __syncthreads();
    }

    // ---- sg GEMV2: h(128) @ sg_w2 -> osum
    {
        float acc = 0.f;
        const int k0 = q * 32;
        #pragma unroll 8
        for (int kk = 0; kk < 32; ++kk)
            acc = fmaf(hbuf[k0 + kk], sg_w2[(k0 + kk) * D + d], acc);
        part[q][d] = acc;
        __syncthreads();
        if (q == 0) osum[d] = part[0][d] + part[1][d] + part[2][d] + part[3][d] + sg_b2[d];
        __syncthreads();
    }

    // ---- mf GEMV1: meta(16) @ mf_w1 -> h2
    {
        float acc = 0.f;
        const int k0 = q * 4;
        #pragma unroll
        for (int kk = 0; kk < 4; ++kk)
            acc = fmaf(meta[b * MM + k0 + kk], mf_w1[(k0 + kk) * D + d], acc);
        part[q][d] = acc;
        __syncthreads();
    }
    {
        float h = 0.f;
        if (q == 0) h = part[0][d] + part[1][d] + part[2][d] + part[3][d] + mf_b1[d];
        float mu  = block_sum_q0(h, t, q, d, red) * (1.f / D);
        float cd  = (q == 0) ? (h - mu) : 0.f;
        float var = block_sum_q0(cd * cd, t, q, d, red) * (1.f / D);
        if (q == 0) hbuf[d] = gelu_f(cd * rsqrtf(var + 1e-5f) * mf_g[d] + mf_bt[d]);
        __syncthreads();
    }

    // ---- mf GEMV2 + sg_emb output + cx input assembly
    {
        float acc = 0.f;
        const int k0 = q * 32;
        #pragma unroll 8
        for (int kk = 0; kk < 32; ++kk)
            acc = fmaf(hbuf[k0 + kk], mf_w2[(k0 + kk) * D + d], acc);
        part[q][d] = acc;
        __syncthreads();
        if (q == 0) {
            float sg = osum[d] + part[0][d] + part[1][d] + part[2][d] + part[3][d] + mf_b2[d];
            out[b * D + d] = sg;
            xbuf[d] = sg;
        } else if (q == 1) {
            xbuf[D + d] = graph_emb[b * D + d];
        }
        __syncthreads();
    }

    // ---- cx GEMV1: [sg_emb, graph_emb](256) @ cx_w1 -> GELU
    {
        float acc = 0.f;
        const int k0 = q * 64;
        #pragma unroll 8
        for (int kk = 0; kk < 64; ++kk)
            acc = fmaf(xbuf[k0 + kk], cx_w1[(k0 + kk) * D + d], acc);
        part[q][d] = acc;
        __syncthreads();
        if (q == 0) hbuf[d] = gelu_f(part[0][d] + part[1][d] + part[2][d] + part[3][d] + cx_b1[d]);
        __syncthreads();
    }

    // ---- cx GEMV2 -> ctxt output
    {
        float acc = 0.f;
        const int k0 = q * 32;
        #pragma unroll 8
        for (int kk = 0; kk < 32; ++kk)
            acc = fmaf(hbuf[k0 + kk], cx_w2[(k0 + kk) * D + d], acc);
        part[q][d] = acc;
        __syncthreads();
        if (q == 0)
            out[BS * D + b * D + d] = part[0][d] + part[1][d] + part[2][d] + part[3][d] + cx_b2[d];
    }
}

extern "C" void kernel_launch(void* const* d_in, const int* in_sizes, int n_in,
                              void* d_out, int out_size, void* d_ws, size_t ws_size,
                              hipStream_t stream) {
    const float* node_emb  = (const float*)d_in[0];
    const float* graph_emb = (const float*)d_in[1];
    const int*   sg_idx    = (const int*)d_in[2];
    const float* meta      = (const float*)d_in[3];
    const float* sg_w1 = (const float*)d_in[4];
    const float* sg_b1 = (const float*)d_in[5];
    const float* sg_g  = (const float*)d_in[6];
    const float* sg_bt = (const float*)d_in[7];
    const float* sg_w2 = (const float*)d_in[8];
    const float* sg_b2 = (const float*)d_in[9];
    const float* mf_w1 = (const float*)d_in[10];
    const float* mf_b1 = (const float*)d_in[11];
    const float* mf_g  = (const float*)d_in[12];
    const float* mf_bt = (const float*)d_in[13];
    const float* mf_w2 = (const float*)d_in[14];
    const float* mf_b2 = (const float*)d_in[15];
    const float* cx_w1 = (const float*)d_in[16];
    const float* cx_b1 = (const float*)d_in[17];
    const float* cx_w2 = (const float*)d_in[18];
    const float* cx_b2 = (const float*)d_in[19];

    float* out    = (float*)d_out;
    float* ws     = (float*)d_ws;
    float* ws_sum = ws;                       // BS*SPLIT*D floats
    float* ws_max = ws + BS * SPLIT * D;      // BS*SPLIT*D floats (total 1.6 MB)

    pool_kernel<<<BS * SPLIT, 256, 0, stream>>>(node_emb, sg_idx, ws_sum, ws_max);
    mlp_kernel<<<BS, 512, 0, stream>>>(ws_sum, ws_max, graph_emb, meta,
        sg_w1, sg_b1, sg_g, sg_bt, sg_w2, sg_b2,
        mf_w1, mf_b1, mf_g, mf_bt, mf_w2, mf_b2,
        cx_w1, cx_b1, cx_w2, cx_b2, out);
}

// Round 4
// 23.494 us; speedup vs baseline: 1.9441x; 1.2204x over previous
//
#include <hip/hip_runtime.h>
#include <math.h>

#define BS    64
#define NPTS  10000
#define D     128
#define MM    16
#define SG    1000
#define ROWG  32     // 1024 threads = 32 row-groups x 32 lanes
#define QS    8      // 8-way K-split in the MLP phase (1024 = 8 x 128)

__device__ __forceinline__ float gelu_f(float x) {
    // JAX default: approximate (tanh) GELU
    float x3 = x * x * x;
    return 0.5f * x * (1.0f + tanhf(0.7978845608028654f * (x + 0.044715f * x3)));
}

// Sum over the 128 h-values held by the q==0 threads (d = 0..127).
// ALL threads must call (contains __syncthreads). Returns the total.
__device__ __forceinline__ float block_sum_q0(float h, int t, int q, int d, float* red) {
    __syncthreads();
    if (q == 0) red[d] = h;
    __syncthreads();
    if (t < 64) {
        float v = red[t] + red[t + 64];
        #pragma unroll
        for (int off = 32; off; off >>= 1) v += __shfl_xor(v, off, 64);
        if (t == 0) red[0] = v;
    }
    __syncthreads();
    return red[0];
}

__global__ __launch_bounds__(1024) void fused_kernel(
    const float* __restrict__ node_emb, const int* __restrict__ sg_idx,
    const float* __restrict__ graph_emb, const float* __restrict__ meta,
    const float* __restrict__ sg_w1, const float* __restrict__ sg_b1,
    const float* __restrict__ sg_g,  const float* __restrict__ sg_bt,
    const float* __restrict__ sg_w2, const float* __restrict__ sg_b2,
    const float* __restrict__ mf_w1, const float* __restrict__ mf_b1,
    const float* __restrict__ mf_g,  const float* __restrict__ mf_bt,
    const float* __restrict__ mf_w2, const float* __restrict__ mf_b2,
    const float* __restrict__ cx_w1, const float* __restrict__ cx_b1,
    const float* __restrict__ cx_w2, const float* __restrict__ cx_b2,
    float* __restrict__ out)
{
    const int b = blockIdx.x;
    const int t = threadIdx.x;

    __shared__ int   idx_lds[SG];
    __shared__ float ssum[ROWG][D];   // 16 KB
    __shared__ float smax[ROWG][D];   // 16 KB
    __shared__ float xbuf[2 * D];
    __shared__ float part[QS][D];
    __shared__ float hbuf[D];
    __shared__ float osum[D];
    __shared__ float red[D];

    // ---- stage indices to LDS (coalesced, one load/thread)
    if (t < SG) idx_lds[t] = sg_idx[b * SG + t];
    __syncthreads();

    // ---- gather + pool: row-group g handles rows g, g+32, ...
    {
        const int g = t >> 5;    // 0..31
        const int c = t & 31;    // channel quad
        const float* __restrict__ base = node_emb + (size_t)b * NPTS * D;

        float4 s = make_float4(0.f, 0.f, 0.f, 0.f);
        float4 m = make_float4(-INFINITY, -INFINITY, -INFINITY, -INFINITY);

        #pragma unroll 8
        for (int j = g; j < SG; j += ROWG) {
            int id = idx_lds[j];
            float4 v = *(const float4*)(base + (size_t)id * D + (c << 2));
            // node_emb[:,0] is the zero vector (depot sentinel)
            float msk = (id != 0) ? 1.f : 0.f;
            v.x *= msk; v.y *= msk; v.z *= msk; v.w *= msk;
            s.x += v.x; s.y += v.y; s.z += v.z; s.w += v.w;
            m.x = fmaxf(m.x, v.x); m.y = fmaxf(m.y, v.y);
            m.z = fmaxf(m.z, v.z); m.w = fmaxf(m.w, v.w);
        }
        *(float4*)&ssum[g][c * 4] = s;
        *(float4*)&smax[g][c * 4] = m;
    }
    __syncthreads();

    const int q = t >> 7;    // 0..7
    const int d = t & 127;   // output channel

    // ---- tree-reduce 32 row-groups -> pooled (sum | max) in xbuf
    {
        float rs = ssum[q * 4 + 0][d] + ssum[q * 4 + 1][d]
                 + ssum[q * 4 + 2][d] + ssum[q * 4 + 3][d];
        float rm = fmaxf(fmaxf(smax[q * 4 + 0][d], smax[q * 4 + 1][d]),
                         fmaxf(smax[q * 4 + 2][d], smax[q * 4 + 3][d]));
        __syncthreads();
        ssum[q][d] = rs;
        smax[q][d] = rm;
        __syncthreads();
        if (q == 0) {
            float fs = 0.f;
            #pragma unroll
            for (int r = 0; r < QS; ++r) fs += ssum[r][d];
            xbuf[d] = fs;
        } else if (q == 1) {
            float fm = -INFINITY;
            #pragma unroll
            for (int r = 0; r < QS; ++r) fm = fmaxf(fm, smax[r][d]);
            xbuf[D + d] = fm;
        }
        __syncthreads();
    }

    // ---- sg GEMV1: pooled(256) @ sg_w1
    {
        float acc = 0.f;
        const int k0 = q * 32;
        #pragma unroll 8
        for (int kk = 0; kk < 32; ++kk)
            acc = fmaf(xbuf[k0 + kk], sg_w1[(k0 + kk) * D + d], acc);
        part[q][d] = acc;
        __syncthreads();
    }
    {   // LN + GELU
        float h = 0.f;
        if (q == 0) {
            #pragma unroll
            for (int r = 0; r < QS; ++r) h += part[r][d];
            h += sg_b1[d];
        }
        float mu  = block_sum_q0(h, t, q, d, red) * (1.f / D);
        float cd  = (q == 0) ? (h - mu) : 0.f;
        float var = block_sum_q0(cd * cd, t, q, d, red) * (1.f / D);
        if (q == 0) hbuf[d] = gelu_f(cd * rsqrtf(var + 1e-5f) * sg_g[d] + sg_bt[d]);
        __syncthreads();
    }

    // ---- sg GEMV2: h(128) @ sg_w2 -> osum
    {
        float acc = 0.f;
        const int k0 = q * 16;
        #pragma unroll 8
        for (int kk = 0; kk < 16; ++kk)
            acc = fmaf(hbuf[k0 + kk], sg_w2[(k0 + kk) * D + d], acc);
        part[q][d] = acc;
        __syncthreads();
        if (q == 0) {
            float o = sg_b2[d];
            #pragma unroll
            for (int r = 0; r < QS; ++r) o += part[r][d];
            osum[d] = o;
        }
        __syncthreads();
    }

    // ---- mf GEMV1: meta(16) @ mf_w1
    {
        float acc = 0.f;
        const int k0 = q * 2;
        #pragma unroll
        for (int kk = 0; kk < 2; ++kk)
            acc = fmaf(meta[b * MM + k0 + kk], mf_w1[(k0 + kk) * D + d], acc);
        part[q][d] = acc;
        __syncthreads();
    }
    {   // LN + GELU
        float h = 0.f;
        if (q == 0) {
            #pragma unroll
            for (int r = 0; r < QS; ++r) h += part[r][d];
            h += mf_b1[d];
        }
        float mu  = block_sum_q0(h, t, q, d, red) * (1.f / D);
        float cd  = (q == 0) ? (h - mu) : 0.f;
        float var = block_sum_q0(cd * cd, t, q, d, red) * (1.f / D);
        if (q == 0) hbuf[d] = gelu_f(cd * rsqrtf(var + 1e-5f) * mf_g[d] + mf_bt[d]);
        __syncthreads();
    }

    // ---- mf GEMV2 + sg_emb output + cx input assembly
    {
        float acc = 0.f;
        const int k0 = q * 16;
        #pragma unroll 8
        for (int kk = 0; kk < 16; ++kk)
            acc = fmaf(hbuf[k0 + kk], mf_w2[(k0 + kk) * D + d], acc);
        part[q][d] = acc;
        __syncthreads();
        if (q == 0) {
            float sg = osum[d] + mf_b2[d];
            #pragma unroll
            for (int r = 0; r < QS; ++r) sg += part[r][d];
            out[b * D + d] = sg;
            xbuf[d] = sg;
        } else if (q == 1) {
            xbuf[D + d] = graph_emb[b * D + d];
        }
        __syncthreads();
    }

    // ---- cx GEMV1: [sg_emb, graph_emb](256) @ cx_w1 -> GELU
    {
        float acc = 0.f;
        const int k0 = q * 32;
        #pragma unroll 8
        for (int kk = 0; kk < 32; ++kk)
            acc = fmaf(xbuf[k0 + kk], cx_w1[(k0 + kk) * D + d], acc);
        part[q][d] = acc;
        __syncthreads();
        if (q == 0) {
            float h = cx_b1[d];
            #pragma unroll
            for (int r = 0; r < QS; ++r) h += part[r][d];
            hbuf[d] = gelu_f(h);
        }
        __syncthreads();
    }

    // ---- cx GEMV2 -> ctxt output
    {
        float acc = 0.f;
        const int k0 = q * 16;
        #pragma unroll 8
        for (int kk = 0; kk < 16; ++kk)
            acc = fmaf(hbuf[k0 + kk], cx_w2[(k0 + kk) * D + d], acc);
        part[q][d] = acc;
        __syncthreads();
        if (q == 0) {
            float o = cx_b2[d];
            #pragma unroll
            for (int r = 0; r < QS; ++r) o += part[r][d];
            out[BS * D + b * D + d] = o;
        }
    }
}

extern "C" void kernel_launch(void* const* d_in, const int* in_sizes, int n_in,
                              void* d_out, int out_size, void* d_ws, size_t ws_size,
                              hipStream_t stream) {
    const float* node_emb  = (const float*)d_in[0];
    const float* graph_emb = (const float*)d_in[1];
    const int*   sg_idx    = (const int*)d_in[2];
    const float* meta      = (const float*)d_in[3];
    const float* sg_w1 = (const float*)d_in[4];
    const float* sg_b1 = (const float*)d_in[5];
    const float* sg_g  = (const float*)d_in[6];
    const float* sg_bt = (const float*)d_in[7];
    const float* sg_w2 = (const float*)d_in[8];
    const float* sg_b2 = (const float*)d_in[9];
    const float* mf_w1 = (const float*)d_in[10];
    const float* mf_b1 = (const float*)d_in[11];
    const float* mf_g  = (const float*)d_in[12];
    const float* mf_bt = (const float*)d_in[13];
    const float* mf_w2 = (const float*)d_in[14];
    const float* mf_b2 = (const float*)d_in[15];
    const float* cx_w1 = (const float*)d_in[16];
    const float* cx_b1 = (const float*)d_in[17];
    const float* cx_w2 = (const float*)d_in[18];
    const float* cx_b2 = (const float*)d_in[19];

    float* out = (float*)d_out;

    fused_kernel<<<BS, 1024, 0, stream>>>(node_emb, sg_idx, graph_emb, meta,
        sg_w1, sg_b1, sg_g, sg_bt, sg_w2, sg_b2,
        mf_w1, mf_b1, mf_g, mf_bt, mf_w2, mf_b2,
        cx_w1, cx_b1, cx_w2, cx_b2, out);
}